// Round 1
// baseline (421.798 us; speedup 1.0000x reference)
//
#include <hip/hip_runtime.h>
#include <hip/hip_bf16.h>

typedef __bf16 bf16;
typedef __bf16 bf16x8 __attribute__((ext_vector_type(8)));
typedef __bf16 bf16x4 __attribute__((ext_vector_type(4)));
typedef float  f32x4  __attribute__((ext_vector_type(4)));

#define MFMA16(A,B,C) __builtin_amdgcn_mfma_f32_16x16x32_bf16(A,B,C,0,0,0)

// Problem constants (B=2, S=2048, NX=1024, H=16, D=64)
static constexpr int SEQ = 2048;
static constexpr int NXC = 1024;

// ---------------- f32 -> bf16 conversion (vectorized) ----------------
__global__ __launch_bounds__(256) void f2b_kernel(const float* __restrict__ in,
                                                  bf16* __restrict__ out, int n4) {
  int i = blockIdx.x * blockDim.x + threadIdx.x;
  if (i < n4) {
    float4 v = ((const float4*)in)[i];
    bf16x4 o;
    o[0] = (bf16)v.x; o[1] = (bf16)v.y; o[2] = (bf16)v.z; o[3] = (bf16)v.w;
    ((bf16x4*)out)[i] = o;
  }
}

// ---------------- bf16 MFMA GEMM, 128x128 tile, BK=32 ----------------
// A: [M x K] row-major bf16. Bm: [K x N] row-major bf16.
// MODE 0: qkv epilogue -> q (scaled 1/8) [BH][S][D], k [BH][S][D], v^T [BH][D][S]
// MODE 1: f32 out + bias
template<int MODE>
__global__ __launch_bounds__(256) void gemm_bf16(
    const bf16* __restrict__ A, const bf16* __restrict__ Bm,
    const float* __restrict__ bias,
    bf16* __restrict__ qb, bf16* __restrict__ kb, bf16* __restrict__ vtb,
    float* __restrict__ outf, int K, int N)
{
  __shared__ bf16 As[128][40];   // padded +8 to break bank conflicts
  __shared__ bf16 Bs[128][40];   // stored transposed: [n][k]

  const int tid  = threadIdx.x;
  const int lane = tid & 63;
  const int w    = tid >> 6;
  const int m0   = blockIdx.y * 128;
  const int n0   = blockIdx.x * 128;
  const int wrow = (w >> 1) * 64;
  const int wcol = (w & 1) * 64;
  const int g    = lane >> 4;
  const int c16  = lane & 15;

  f32x4 acc[4][4];
  #pragma unroll
  for (int i = 0; i < 4; ++i)
    #pragma unroll
    for (int j = 0; j < 4; ++j)
      acc[i][j] = f32x4{0.f, 0.f, 0.f, 0.f};

  const int arow = tid >> 2;         // 0..63
  const int acol = (tid & 3) * 8;    // 0,8,16,24
  const int bk   = tid >> 4;         // 0..15
  const int bn   = (tid & 15) * 8;   // 0..120

  for (int k0 = 0; k0 < K; k0 += 32) {
    // stage A tile [128 x 32]
    #pragma unroll
    for (int p = 0; p < 2; ++p) {
      int r = arow + p * 64;
      bf16x8 v = *(const bf16x8*)&A[(size_t)(m0 + r) * K + k0 + acol];
      *(bf16x8*)&As[r][acol] = v;
    }
    // stage B tile [32 x 128], transposed into Bs[n][k]
    #pragma unroll
    for (int p = 0; p < 2; ++p) {
      int kk = bk + p * 16;
      bf16x8 v = *(const bf16x8*)&Bm[(size_t)(k0 + kk) * N + n0 + bn];
      #pragma unroll
      for (int e = 0; e < 8; ++e) Bs[bn + e][kk] = v[e];
    }
    __syncthreads();

    bf16x8 af[4], bfr[4];
    #pragma unroll
    for (int i = 0; i < 4; ++i)
      af[i] = *(const bf16x8*)&As[wrow + i * 16 + c16][g * 8];
    #pragma unroll
    for (int j = 0; j < 4; ++j)
      bfr[j] = *(const bf16x8*)&Bs[wcol + j * 16 + c16][g * 8];
    #pragma unroll
    for (int i = 0; i < 4; ++i)
      #pragma unroll
      for (int j = 0; j < 4; ++j)
        acc[i][j] = MFMA16(af[i], bfr[j], acc[i][j]);
    __syncthreads();
  }

  // epilogue. C layout: row = (lane>>4)*4 + r, col = lane&15  [m89-verified]
  #pragma unroll
  for (int i = 0; i < 4; ++i) {
    #pragma unroll
    for (int j = 0; j < 4; ++j) {
      #pragma unroll
      for (int r = 0; r < 4; ++r) {
        int gm = m0 + wrow + i * 16 + g * 4 + r;
        int gn = n0 + wcol + j * 16 + c16;
        float v = acc[i][j][r] + bias[gn];
        if (MODE == 0) {
          int which = gn >> 10;          // 0=q 1=k 2=v (uniform per block)
          int cc = gn & 1023;
          int hh = cc >> 6, dd = cc & 63;
          int bb = gm >> 11, ss = gm & 2047;
          int bh = bb * 16 + hh;
          if (which == 0)
            qb[((size_t)bh * SEQ + ss) * 64 + dd] = (bf16)(v * 0.125f);
          else if (which == 1)
            kb[((size_t)bh * SEQ + ss) * 64 + dd] = (bf16)v;
          else
            vtb[((size_t)bh * 64 + dd) * SEQ + ss] = (bf16)v;  // transposed
        } else {
          outf[(size_t)gm * N + gn] = v;
        }
      }
    }
  }
}

// ---------------- flash attention: 1 wave = 16 q-rows ----------------
// q,k: [BH=32][S=2048][64] bf16 (q pre-scaled by 1/8). vt: [BH][64][S] bf16.
// aout: [B=2][S][NX=1024] bf16 (heads merged).
__global__ __launch_bounds__(256) void attn_kernel(
    const bf16* __restrict__ q, const bf16* __restrict__ k,
    const bf16* __restrict__ vt, bf16* __restrict__ aout)
{
  __shared__ bf16 plds[4][16][40];   // wave-private P transpose tiles

  const int tid  = threadIdx.x;
  const int lane = tid & 63;
  const int w    = tid >> 6;
  const int wid  = blockIdx.x * 4 + w;    // 0..4095
  const int bh   = wid >> 7;              // 0..31
  const int qt   = wid & 127;             // q tile index (16 rows each)
  const int g    = lane >> 4;
  const int c16  = lane & 15;

  const f32x4 zero4 = {0.f, 0.f, 0.f, 0.f};

  // Q fragments (A-operand): row = c16, k(d) = 8*g + j (+32 for chunk 1)
  bf16x8 qf[2];
  {
    const size_t qbase = ((size_t)bh * SEQ + qt * 16 + c16) * 64;
    qf[0] = *(const bf16x8*)&q[qbase + g * 8];
    qf[1] = *(const bf16x8*)&q[qbase + 32 + g * 8];
  }

  f32x4 Oacc[4];
  #pragma unroll
  for (int nf = 0; nf < 4; ++nf) Oacc[nf] = zero4;
  float mrow[4], lsum[4];
  #pragma unroll
  for (int r = 0; r < 4; ++r) { mrow[r] = -INFINITY; lsum[r] = 0.f; }

  const int qrow0  = qt * 16 + g * 4;
  const int nsteps = (qt * 16 + 16 + 31) >> 5;   // causal: only kv <= q rows
  bf16* pw = &plds[w][0][0];

  for (int kt = 0; kt < nsteps; ++kt) {
    const int kv0 = kt * 32;
    // S = Q K^T  (two 16-col kv tiles)
    f32x4 s[2];
    #pragma unroll
    for (int t = 0; t < 2; ++t) {
      const size_t kbase = ((size_t)bh * SEQ + kv0 + t * 16 + c16) * 64;
      bf16x8 kf0 = *(const bf16x8*)&k[kbase + g * 8];
      bf16x8 kf1 = *(const bf16x8*)&k[kbase + 32 + g * 8];
      s[t] = MFMA16(qf[0], kf0, zero4);
      s[t] = MFMA16(qf[1], kf1, s[t]);
    }
    // causal mask
    #pragma unroll
    for (int t = 0; t < 2; ++t)
      #pragma unroll
      for (int r = 0; r < 4; ++r) {
        int kvidx = kv0 + t * 16 + c16;
        if (kvidx > qrow0 + r) s[t][r] = -1e30f;
      }
    // online softmax: row max over the 16 lanes of the group
    float mx[4];
    #pragma unroll
    for (int r = 0; r < 4; ++r) mx[r] = fmaxf(s[0][r], s[1][r]);
    #pragma unroll
    for (int off = 1; off < 16; off <<= 1)
      #pragma unroll
      for (int r = 0; r < 4; ++r) mx[r] = fmaxf(mx[r], __shfl_xor(mx[r], off));
    float sc[4];
    #pragma unroll
    for (int r = 0; r < 4; ++r) {
      float mn = fmaxf(mrow[r], mx[r]);
      sc[r] = __expf(mrow[r] - mn);
      mrow[r] = mn;
    }
    float p[2][4];
    #pragma unroll
    for (int t = 0; t < 2; ++t)
      #pragma unroll
      for (int r = 0; r < 4; ++r) p[t][r] = __expf(s[t][r] - mrow[r]);
    #pragma unroll
    for (int r = 0; r < 4; ++r) lsum[r] = lsum[r] * sc[r] + p[0][r] + p[1][r];
    #pragma unroll
    for (int nf = 0; nf < 4; ++nf)
      #pragma unroll
      for (int r = 0; r < 4; ++r) Oacc[nf][r] *= sc[r];

    // transpose P through wave-private LDS: C-layout -> A-operand layout
    #pragma unroll
    for (int t = 0; t < 2; ++t)
      #pragma unroll
      for (int r = 0; r < 4; ++r)
        pw[(g * 4 + r) * 40 + t * 16 + c16] = (bf16)p[t][r];
    asm volatile("s_waitcnt lgkmcnt(0)" ::: "memory");
    bf16x8 pa = *(const bf16x8*)&pw[c16 * 40 + g * 8];

    // O += P V   (V^T layout gives contiguous kv per lane)
    #pragma unroll
    for (int nf = 0; nf < 4; ++nf) {
      bf16x8 vf = *(const bf16x8*)&vt[((size_t)bh * 64 + nf * 16 + c16) * SEQ + kv0 + g * 8];
      Oacc[nf] = MFMA16(pa, vf, Oacc[nf]);
    }
  }

  // final row-sum reduction and normalize
  #pragma unroll
  for (int off = 1; off < 16; off <<= 1)
    #pragma unroll
    for (int r = 0; r < 4; ++r) lsum[r] += __shfl_xor(lsum[r], off);

  const int bb = bh >> 4, hh = bh & 15;
  #pragma unroll
  for (int r = 0; r < 4; ++r) {
    float inv = 1.f / lsum[r];
    int srow = qt * 16 + g * 4 + r;
    #pragma unroll
    for (int nf = 0; nf < 4; ++nf)
      aout[((size_t)bb * SEQ + srow) * NXC + hh * 64 + nf * 16 + c16] =
          (bf16)(Oacc[nf][r] * inv);
  }
}

extern "C" void kernel_launch(void* const* d_in, const int* in_sizes, int n_in,
                              void* d_out, int out_size, void* d_ws, size_t ws_size,
                              hipStream_t stream) {
  const float* x      = (const float*)d_in[0];
  // d_in[1] = attention_mask — exactly causal, implemented structurally
  const float* w_attn = (const float*)d_in[2];
  const float* b_attn = (const float*)d_in[3];
  const float* w_proj = (const float*)d_in[4];
  const float* b_proj = (const float*)d_in[5];
  float* out = (float*)d_out;

  // workspace layout (48 MiB total)
  char* p = (char*)d_ws;
  bf16* xb  = (bf16*)p; p += (size_t)4194304 * 2;  // x bf16 [4096][1024]
  bf16* wab = (bf16*)p; p += (size_t)3145728 * 2;  // w_attn bf16 [1024][3072]
  bf16* wpb = (bf16*)p; p += (size_t)1048576 * 2;  // w_proj bf16 [1024][1024]
  bf16* qb  = (bf16*)p; p += (size_t)4194304 * 2;  // q [32][2048][64] (pre-scaled)
  bf16* kb  = (bf16*)p; p += (size_t)4194304 * 2;  // k [32][2048][64]
  bf16* vtb = (bf16*)p; p += (size_t)4194304 * 2;  // v^T [32][64][2048]
  bf16* ab  = (bf16*)p; p += (size_t)4194304 * 2;  // attn out merged [4096][1024]

  f2b_kernel<<<4096, 256, 0, stream>>>(x, xb, 1048576);
  f2b_kernel<<<3072, 256, 0, stream>>>(w_attn, wab, 786432);
  f2b_kernel<<<1024, 256, 0, stream>>>(w_proj, wpb, 262144);

  gemm_bf16<0><<<dim3(24, 32), 256, 0, stream>>>(xb, wab, b_attn, qb, kb, vtb,
                                                 nullptr, 1024, 3072);
  attn_kernel<<<1024, 256, 0, stream>>>(qb, kb, vtb, ab);
  gemm_bf16<1><<<dim3(8, 32), 256, 0, stream>>>(ab, wpb, b_proj, nullptr, nullptr,
                                                nullptr, out, 1024, 1024);
}

// Round 2
// 162.598 us; speedup vs baseline: 2.5941x; 2.5941x over previous
//
#include <hip/hip_runtime.h>
#include <hip/hip_bf16.h>

typedef __bf16 bf16;
typedef __bf16 bf16x8 __attribute__((ext_vector_type(8)));
typedef __bf16 bf16x4 __attribute__((ext_vector_type(4)));
typedef float  f32x4  __attribute__((ext_vector_type(4)));
typedef float  f32x16 __attribute__((ext_vector_type(16)));

#define MFMA16(A,B,C) __builtin_amdgcn_mfma_f32_16x16x32_bf16(A,B,C,0,0,0)
#define MFMA32(A,B,C) __builtin_amdgcn_mfma_f32_32x32x16_bf16(A,B,C,0,0,0)

static constexpr int SEQ = 2048;
static constexpr int NXC = 1024;

static __device__ inline unsigned packb(float lo, float hi) {
  union { bf16 h[2]; unsigned u; } x;
  x.h[0] = (bf16)lo; x.h[1] = (bf16)hi;
  return x.u;
}
static __device__ inline bf16x8 frag_from_words(unsigned a, unsigned b,
                                                unsigned c, unsigned d) {
  union { unsigned u[4]; bf16x8 v; } x;
  x.u[0] = a; x.u[1] = b; x.u[2] = c; x.u[3] = d;
  return x.v;
}

// ---------------- f32 -> bf16 conversion (vectorized) ----------------
__global__ __launch_bounds__(256) void f2b_kernel(const float* __restrict__ in,
                                                  bf16* __restrict__ out, int n4) {
  int i = blockIdx.x * blockDim.x + threadIdx.x;
  if (i < n4) {
    float4 v = ((const float4*)in)[i];
    bf16x4 o;
    o[0] = (bf16)v.x; o[1] = (bf16)v.y; o[2] = (bf16)v.z; o[3] = (bf16)v.w;
    ((bf16x4*)out)[i] = o;
  }
}

// ------------- f32 [R][C] -> bf16 transposed [C][R] -------------
__global__ __launch_bounds__(256) void tr_f2b(const float* __restrict__ in,
                                              bf16* __restrict__ out, int R, int C) {
  __shared__ bf16 t[64][72];
  const int c0 = blockIdx.x * 64, r0 = blockIdx.y * 64;
  const int tid = threadIdx.x;
  const int lr = tid >> 4, lc = (tid & 15) * 4;
  #pragma unroll
  for (int p = 0; p < 4; ++p) {
    int rr = lr + p * 16;
    float4 v = *(const float4*)&in[(size_t)(r0 + rr) * C + c0 + lc];
    t[lc + 0][rr] = (bf16)v.x; t[lc + 1][rr] = (bf16)v.y;
    t[lc + 2][rr] = (bf16)v.z; t[lc + 3][rr] = (bf16)v.w;
  }
  __syncthreads();
  const int orow = tid >> 3, ocol = (tid & 7) * 8;
  #pragma unroll
  for (int p = 0; p < 2; ++p) {
    int rr = orow + p * 32;
    *(bf16x8*)&out[(size_t)(c0 + rr) * R + r0 + ocol] = *(const bf16x8*)&t[rr][ocol];
  }
}

// ---------------- bf16 MFMA GEMM, 128x128 tile, BK=32, B^T input ----------------
// A: [M x K] row-major. BT: [N x K] row-major. Both staged with ds_write_b128.
template<int MODE>
__global__ __launch_bounds__(256) void gemm_bt(
    const bf16* __restrict__ A, const bf16* __restrict__ BT,
    const float* __restrict__ bias,
    bf16* __restrict__ qb, bf16* __restrict__ kb, bf16* __restrict__ vtb,
    float* __restrict__ outf, int K, int N)
{
  __shared__ bf16 As[128][40];
  __shared__ bf16 Bs[128][40];

  const int tid  = threadIdx.x;
  const int lane = tid & 63;
  const int w    = tid >> 6;
  const int m0   = blockIdx.y * 128;
  const int n0   = blockIdx.x * 128;
  const int wrow = (w >> 1) * 64;
  const int wcol = (w & 1) * 64;
  const int g    = lane >> 4;
  const int c16  = lane & 15;

  f32x4 acc[4][4];
  #pragma unroll
  for (int i = 0; i < 4; ++i)
    #pragma unroll
    for (int j = 0; j < 4; ++j)
      acc[i][j] = f32x4{0.f, 0.f, 0.f, 0.f};

  const int srow = tid >> 2;
  const int scol = (tid & 3) * 8;

  for (int k0 = 0; k0 < K; k0 += 32) {
    #pragma unroll
    for (int p = 0; p < 2; ++p) {
      int r = srow + p * 64;
      *(bf16x8*)&As[r][scol] = *(const bf16x8*)&A[(size_t)(m0 + r) * K + k0 + scol];
      *(bf16x8*)&Bs[r][scol] = *(const bf16x8*)&BT[(size_t)(n0 + r) * K + k0 + scol];
    }
    __syncthreads();

    bf16x8 af[4], bfr[4];
    #pragma unroll
    for (int i = 0; i < 4; ++i)
      af[i] = *(const bf16x8*)&As[wrow + i * 16 + c16][g * 8];
    #pragma unroll
    for (int j = 0; j < 4; ++j)
      bfr[j] = *(const bf16x8*)&Bs[wcol + j * 16 + c16][g * 8];
    #pragma unroll
    for (int i = 0; i < 4; ++i)
      #pragma unroll
      for (int j = 0; j < 4; ++j)
        acc[i][j] = MFMA16(af[i], bfr[j], acc[i][j]);
    __syncthreads();
  }

  // epilogue. C layout: row = (lane>>4)*4 + r, col = lane&15
  #pragma unroll
  for (int i = 0; i < 4; ++i) {
    #pragma unroll
    for (int j = 0; j < 4; ++j) {
      #pragma unroll
      for (int r = 0; r < 4; ++r) {
        int gm = m0 + wrow + i * 16 + g * 4 + r;
        int gn = n0 + wcol + j * 16 + c16;
        float v = acc[i][j][r] + bias[gn];
        if (MODE == 0) {
          int which = gn >> 10;
          int cc = gn & 1023;
          int hh = cc >> 6, dd = cc & 63;
          int bb = gm >> 11, ss = gm & 2047;
          int bh = bb * 16 + hh;
          if (which == 0)
            qb[((size_t)bh * SEQ + ss) * 64 + dd] = (bf16)(v * 0.125f);
          else if (which == 1)
            kb[((size_t)bh * SEQ + ss) * 64 + dd] = (bf16)v;
          else
            vtb[((size_t)bh * 64 + dd) * SEQ + ss] = (bf16)v;
        } else {
          outf[(size_t)gm * N + gn] = v;
        }
      }
    }
  }
}

// ---------------- flash attention v2: swapped QK^T, 1 wave = 32 q-rows ----------------
// q,k: [BH=32][S][64] bf16 (q pre-scaled 1/8). vt: [BH][64][S] bf16.
// Per wave: S^T[kv][q] = mfma32(K, Q^T); lane holds full P-row (q = lane&31).
// PV as O^T[d][q] = mfma32(V^T, P^T) so softmax state stays lane-local.
__global__ __launch_bounds__(64) void attn2_kernel(
    const bf16* __restrict__ q, const bf16* __restrict__ k,
    const bf16* __restrict__ vt, bf16* __restrict__ aout)
{
  __shared__ bf16 ot[32][72];

  const int lane = threadIdx.x & 63;
  const int hi   = lane >> 5;
  const int q_l  = lane & 31;
  const int wid  = blockIdx.x;
  const int bh   = wid & 31;                 // head-major so long tiles start first
  const int qt   = 63 - (wid >> 5);          // descending work
  const int qr0  = qt * 32;
  const int qg   = qr0 + q_l;
  const int nsteps = (qt + 2) >> 1;

  // Q as B-operand frags: lane holds Q[q = qr0+q_l][d = 16c + 8*hi + j]
  bf16x8 qf[4];
  {
    const bf16* qp = q + ((size_t)bh * SEQ + qr0 + q_l) * 64 + hi * 8;
    #pragma unroll
    for (int c = 0; c < 4; ++c) qf[c] = *(const bf16x8*)(qp + c * 16);
  }

  f32x16 Ot0 = (f32x16)0.f, Ot1 = (f32x16)0.f;
  float mrun = -INFINITY, lrun = 0.f;

  const bf16* kbase = k + ((size_t)bh * SEQ + q_l) * 64 + hi * 8;
  const bf16* vbase = vt + ((size_t)bh * 64 + q_l) * SEQ + hi * 8;

  for (int kt = 0; kt < nsteps; ++kt) {
    const int kv0 = kt << 6;
    f32x16 st0 = (f32x16)0.f, st1 = (f32x16)0.f;

    // S^T = K Q^T  (two 32-kv tiles, 4 d-chunks each)
    const bf16* kp = kbase + (size_t)kv0 * 64;
    #pragma unroll
    for (int c = 0; c < 4; ++c) {
      bf16x8 kf0 = *(const bf16x8*)(kp + c * 16);
      bf16x8 kf1 = *(const bf16x8*)(kp + 32 * 64 + c * 16);
      st0 = MFMA32(kf0, qf[c], st0);
      st1 = MFMA32(kf1, qf[c], st1);
    }

    // causal mask (last step only). kv_local = (r&3)+8*(r>>2)+4*hi
    if (kt == nsteps - 1) {
      #pragma unroll
      for (int r = 0; r < 16; ++r) {
        int kvl = kv0 + (r & 3) + 8 * (r >> 2) + 4 * hi;
        if (kvl > qg)      st0[r] = -1e30f;
        if (kvl + 32 > qg) st1[r] = -1e30f;
      }
    }

    // row max: in-register tree + one cross-half swap
    float m8[8];
    #pragma unroll
    for (int r = 0; r < 8; ++r)
      m8[r] = fmaxf(fmaxf(st0[r], st0[r + 8]), fmaxf(st1[r], st1[r + 8]));
    #pragma unroll
    for (int r = 0; r < 4; ++r) m8[r] = fmaxf(m8[r], m8[r + 4]);
    float pmax = fmaxf(fmaxf(m8[0], m8[1]), fmaxf(m8[2], m8[3]));
    pmax = fmaxf(pmax, __shfl_xor(pmax, 32));

    const float mnew = fmaxf(mrun, pmax);
    const float sc = __expf(mrun - mnew);
    mrun = mnew;

    #pragma unroll
    for (int r = 0; r < 16; ++r) {
      st0[r] = __expf(st0[r] - mnew);
      st1[r] = __expf(st1[r] - mnew);
    }

    float s8[8];
    #pragma unroll
    for (int r = 0; r < 8; ++r)
      s8[r] = (st0[r] + st0[r + 8]) + (st1[r] + st1[r + 8]);
    #pragma unroll
    for (int r = 0; r < 4; ++r) s8[r] += s8[r + 4];
    float rs = (s8[0] + s8[1]) + (s8[2] + s8[3]);
    rs += __shfl_xor(rs, 32);
    lrun = lrun * sc + rs;
    Ot0 *= sc;
    Ot1 *= sc;

    // pack P to bf16 words; redistribute to B-operand layout via permlane32_swap
    unsigned pw[16];
    #pragma unroll
    for (int m = 0; m < 8; ++m) {
      pw[m]     = packb(st0[2 * m], st0[2 * m + 1]);
      pw[8 + m] = packb(st1[2 * m], st1[2 * m + 1]);
    }

    const bf16* vp = vbase + kv0;
    #pragma unroll
    for (int t = 0; t < 2; ++t) {
      #pragma unroll
      for (int h = 0; h < 2; ++h) {
        auto sa = __builtin_amdgcn_permlane32_swap((int)pw[t * 8 + 4 * h + 0],
                                                   (int)pw[t * 8 + 4 * h + 2], false, false);
        auto sb = __builtin_amdgcn_permlane32_swap((int)pw[t * 8 + 4 * h + 1],
                                                   (int)pw[t * 8 + 4 * h + 3], false, false);
        bf16x8 pb = frag_from_words((unsigned)sa[0], (unsigned)sb[0],
                                    (unsigned)sa[1], (unsigned)sb[1]);
        bf16x8 va = *(const bf16x8*)(vp + t * 32 + h * 16);
        bf16x8 vb = *(const bf16x8*)(vp + (size_t)32 * SEQ + t * 32 + h * 16);
        Ot0 = MFMA32(va, pb, Ot0);
        Ot1 = MFMA32(vb, pb, Ot1);
      }
    }
  }

  // normalize (lane-local: q = lane&31 on both halves) and store via LDS transpose
  const float inv = 1.f / lrun;
  #pragma unroll
  for (int r = 0; r < 16; ++r) {
    int d = (r & 3) + 8 * (r >> 2) + 4 * hi;
    ot[q_l][d]      = (bf16)(Ot0[r] * inv);
    ot[q_l][32 + d] = (bf16)(Ot1[r] * inv);
  }
  __syncthreads();

  const int bb = bh >> 4, hh = bh & 15;
  const int qrow = lane >> 1, half = lane & 1;
  const bf16* src = &ot[qrow][half * 32];
  bf16* dst = aout + ((size_t)bb * SEQ + qr0 + qrow) * NXC + hh * 64 + half * 32;
  #pragma unroll
  for (int e = 0; e < 4; ++e)
    *(bf16x8*)(dst + e * 8) = *(const bf16x8*)(src + e * 8);
}

extern "C" void kernel_launch(void* const* d_in, const int* in_sizes, int n_in,
                              void* d_out, int out_size, void* d_ws, size_t ws_size,
                              hipStream_t stream) {
  const float* x      = (const float*)d_in[0];
  // d_in[1] = attention_mask — exactly causal, implemented structurally
  const float* w_attn = (const float*)d_in[2];
  const float* b_attn = (const float*)d_in[3];
  const float* w_proj = (const float*)d_in[4];
  const float* b_proj = (const float*)d_in[5];
  float* out = (float*)d_out;

  char* p = (char*)d_ws;
  bf16* xb   = (bf16*)p; p += (size_t)4194304 * 2;  // x bf16 [4096][1024]
  bf16* wabT = (bf16*)p; p += (size_t)3145728 * 2;  // w_attn^T bf16 [3072][1024]
  bf16* wpbT = (bf16*)p; p += (size_t)1048576 * 2;  // w_proj^T bf16 [1024][1024]
  bf16* qb   = (bf16*)p; p += (size_t)4194304 * 2;  // q [32][2048][64] (pre-scaled)
  bf16* kb   = (bf16*)p; p += (size_t)4194304 * 2;  // k [32][2048][64]
  bf16* vtb  = (bf16*)p; p += (size_t)4194304 * 2;  // v^T [32][64][2048]
  bf16* ab   = (bf16*)p; p += (size_t)4194304 * 2;  // attn out merged [4096][1024]

  f2b_kernel<<<4096, 256, 0, stream>>>(x, xb, 1048576);
  tr_f2b<<<dim3(48, 16), 256, 0, stream>>>(w_attn, wabT, 1024, 3072);
  tr_f2b<<<dim3(16, 16), 256, 0, stream>>>(w_proj, wpbT, 1024, 1024);

  gemm_bt<0><<<dim3(24, 32), 256, 0, stream>>>(xb, wabT, b_attn, qb, kb, vtb,
                                               nullptr, 1024, 3072);
  attn2_kernel<<<2048, 64, 0, stream>>>(qb, kb, vtb, ab);
  gemm_bt<1><<<dim3(8, 32), 256, 0, stream>>>(ab, wpbT, b_proj, nullptr, nullptr,
                                              nullptr, out, 1024, 1024);
}